// Round 1
// baseline (285.006 us; speedup 1.0000x reference)
//
#include <hip/hip_runtime.h>
#include <math.h>

#define TILE_F 1792    // floats per wave tile; worst-case region ~1770 (level-2, 125x6 ROI)
#define HALF_F 896     // per-buffer floats in the double-buffered (pipelined) path
#define MAXI  7        // serial-path float4 staging iterations: ceil((TILE_F/4)/64)
#define MAXIP 4        // pipelined-path float4 staging iterations: ceil((HALF_F/4)/64)
#define MAXK3 6        // level-3 path word staging iterations: region <= 340 floats <= 384

typedef __attribute__((address_space(3))) void lds_void;
typedef const __attribute__((address_space(1))) void g_void;

__device__ __forceinline__ void dma16(const float* g, float* l) {
  __builtin_amdgcn_global_load_lds((g_void*)g, (lds_void*)l, 16, 0, 0);
}
__device__ __forceinline__ void dma4(const float* g, float* l) {
  __builtin_amdgcn_global_load_lds((g_void*)g, (lds_void*)l, 4, 0, 0);
}
// Counted vmcnt wait: k is wave-uniform; immediate <= actual just-issued count is always safe
// (vmcnt retires in-order, so "outstanding <= k" implies all older loads completed).
__device__ __forceinline__ void wait_vmcnt(int k) {
  switch (k) {
    case 0: asm volatile("s_waitcnt vmcnt(0)" ::: "memory"); break;
    case 1: asm volatile("s_waitcnt vmcnt(1)" ::: "memory"); break;
    case 2: asm volatile("s_waitcnt vmcnt(2)" ::: "memory"); break;
    case 3: asm volatile("s_waitcnt vmcnt(3)" ::: "memory"); break;
    case 4: asm volatile("s_waitcnt vmcnt(4)" ::: "memory"); break;
    case 5: asm volatile("s_waitcnt vmcnt(5)" ::: "memory"); break;
    default: asm volatile("s_waitcnt vmcnt(6)" ::: "memory"); break;
  }
}

// 49-lane bilinear 2x2x(2x2) gather + average + store; arrays are unroll-indexed (registers).
#define COMPUTE_STORE(TP, CC)                                                  \
  if (lane < 49) {                                                             \
    float acc = 0.0f;                                                          \
    _Pragma("unroll")                                                          \
    for (int sy = 0; sy < 2; ++sy) {                                           \
      _Pragma("unroll")                                                        \
      for (int sx = 0; sx < 2; ++sx) {                                         \
        const float w00 = (TP)[rT[sy] + Cc0[sx]];                              \
        const float w01 = (TP)[rT[sy] + Cc1[sx]];                              \
        const float w10 = (TP)[rB[sy] + Cc0[sx]];                              \
        const float w11 = (TP)[rB[sy] + Cc1[sx]];                              \
        const float bil = HY[sy] * (HX[sx] * w00 + LX[sx] * w01)               \
                        + LY[sy] * (HX[sx] * w10 + LX[sx] * w11);              \
        acc += (VY[sy] * VX[sx]) * bil;                                        \
      }                                                                        \
    }                                                                          \
    outp[(CC) * 49] = acc * 0.25f;                                             \
  }

__global__ __launch_bounds__(128) void pooler_kernel(
    const float* __restrict__ f0, const float* __restrict__ f1,
    const float* __restrict__ f2, const float* __restrict__ f3,
    const float* __restrict__ boxes, const int* __restrict__ bidx,
    float* __restrict__ out, int N)
{
  __shared__ __align__(16) float tile[2][TILE_F];  // one tile per wave (2 x HALF_F when pipelined)
  const int tid  = threadIdx.x;
  const int wave = tid >> 6, lane = tid & 63;
  const int n    = blockIdx.y;
  if (n >= N) return;

  // ---- per-box meta (wave-uniform, recomputed by every lane) ----
  const float bx1 = boxes[4*n+0], by1 = boxes[4*n+1];
  const float bx2 = boxes[4*n+2], by2 = boxes[4*n+3];
  const float area = (bx2 - bx1 + 1.0f) * (by2 - by1 + 1.0f);
  const float s    = sqrtf(area);
  int lvl = (int)floorf(4.0f + log2f(s / 224.0f + 1e-6f));
  lvl = lvl < 2 ? 2 : (lvl > 5 ? 5 : lvl);
  const int li = lvl - 2;

  int H, W; const float* feat; float scale;
  switch (li) {
    case 0:  feat = f0; H = 200; W = 304; scale = 0.25f;    break;
    case 1:  feat = f1; H = 100; W = 152; scale = 0.125f;   break;
    case 2:  feat = f2; H = 50;  W = 76;  scale = 0.0625f;  break;
    default: feat = f3; H = 25;  W = 38;  scale = 0.03125f; break;
  }
  const int b = bidx[n];
  const float x1s = bx1 * scale, y1s = by1 * scale;
  const float roiw = fmaxf(bx2 * scale - x1s, 1.0f);
  const float roih = fmaxf(by2 * scale - y1s, 1.0f);
  const float binw = roiw / 7.0f, binh = roih / 7.0f;
  const float Hm1f = (float)(H - 1), Wm1f = (float)(W - 1);
  const int   Hm1  = H - 1,          Wm1  = W - 1;

  // ---- staged region bounds (samples are monotone: first g=0.25, last g=6.75) ----
  const float yA = fminf(fmaxf(y1s + binh * 0.25f, 0.0f), Hm1f);
  const float yB = fminf(fmaxf(y1s + binh * 6.75f, 0.0f), Hm1f);
  const float xA = fminf(fmaxf(x1s + binw * 0.25f, 0.0f), Wm1f);
  const float xB = fminf(fmaxf(x1s + binw * 6.75f, 0.0f), Wm1f);
  const int y_lo  = (int)yA;
  const int y_hi  = min((int)yB + 1, Hm1);
  const int regH  = y_hi - y_lo + 1;
  const int x_lo4 = ((int)xA) & ~3;            // float4-aligned region start
  const int x_hi  = min((int)xB + 1, Wm1);
  const int row4  = ((x_hi - x_lo4 + 4) >> 2); // float4 units per row (>=1)
  const int regW4 = row4 << 2;                 // LDS row stride in floats

  // ---- per-lane bin parameters (channel-invariant; lanes 49..63 compute junk) ----
  const int bin = (lane < 49) ? lane : 0;
  const int ph = bin / 7, pw = bin - (bin / 7) * 7;
  int   rT[2], rB[2], Cc0[2], Cc1[2];
  float HY[2], LY[2], VY[2], HX[2], LX[2], VX[2];
#pragma unroll
  for (int t = 0; t < 2; ++t) {
    {   // y sample index i = 2*ph + t  →  g = ph + 0.25 + 0.5*t
      const float g  = (float)ph + 0.25f + 0.5f * (float)t;
      const float Yf = y1s + binh * g;
      VY[t] = (Yf >= -1.0f && Yf <= (float)H) ? 1.0f : 0.0f;
      const float y = fminf(fmaxf(Yf, 0.0f), Hm1f);
      const int  y0 = (int)y;
      LY[t] = y - (float)y0;  HY[t] = 1.0f - LY[t];
      rT[t] = (y0 - y_lo) * regW4;
      rB[t] = (min(y0 + 1, Hm1) - y_lo) * regW4;
    }
    {   // x sample index j = 2*pw + t
      const float g  = (float)pw + 0.25f + 0.5f * (float)t;
      const float Xf = x1s + binw * g;
      VX[t] = (Xf >= -1.0f && Xf <= (float)W) ? 1.0f : 0.0f;
      const float x = fminf(fmaxf(Xf, 0.0f), Wm1f);
      const int  x0 = (int)x;
      LX[t] = x - (float)x0;  HX[t] = 1.0f - LX[t];
      Cc0[t] = x0 - x_lo4;
      Cc1[t] = min(x0 + 1, Wm1) - x_lo4;
    }
  }

  // ---- pointers ----
  const size_t planeHW = (size_t)H * W;
  const int    cbase   = (blockIdx.x << 5) + (wave << 4);   // 16 channels per wave
  const float* plane0  = feat + ((size_t)(b * 256 + cbase)) * planeHW
                              + (size_t)y_lo * W;
  float*       outp    = out + ((size_t)n * 256 + cbase) * 49 + lane;
  float*       myt     = tile[wave];

  if (li != 3) {
    int cnt4 = regH * row4;
    if (cnt4 > TILE_F / 4) cnt4 = TILE_F / 4;   // safety (analysis: <=~443)

    if (cnt4 <= HALF_F / 4) {
      // ======== pipelined path (~98% of boxes): double-buffered, counted vmcnt ========
      int soff[MAXIP];
#pragma unroll
      for (int i = 0; i < MAXIP; ++i) {
        const int u = lane + (i << 6);
        if (u < cnt4) {
          const int r = u / row4;
          const int c = u - r * row4;
          soff[i] = r * W + x_lo4 + (c << 2);
        } else soff[i] = -1;
      }
      const int K = (cnt4 + 63) >> 6;   // DMA instructions per channel (wave-uniform, <=4)

      // prologue: channel 0 → buffer 0
#pragma unroll
      for (int i = 0; i < MAXIP; ++i)
        if (soff[i] >= 0) dma16(plane0 + soff[i], myt + (i << 8));

      for (int cc = 0; cc < 16; ++cc) {
        // buf[(cc+1)&1] was last read by compute(cc-1): drain LDS reads before DMA overwrites
        asm volatile("s_waitcnt lgkmcnt(0)" ::: "memory");
        if (cc < 15) {
          const float* planeN = plane0 + (size_t)(cc + 1) * planeHW;
          float* bufN = myt + ((cc & 1) ? 0 : HALF_F);      // buffer (cc+1)&1
#pragma unroll
          for (int i = 0; i < MAXIP; ++i)
            if (soff[i] >= 0) dma16(planeN + soff[i], bufN + (i << 8));
          wait_vmcnt(K);    // in-order retire: channel cc's loads (older) are now complete
        } else {
          asm volatile("s_waitcnt vmcnt(0)" ::: "memory");
        }
        const float* bufC = myt + ((cc & 1) ? HALF_F : 0);
        COMPUTE_STORE(bufC, cc)
      }
    } else {
      // ======== serial fallback (rare elongated level-2 boxes): full 1792-float tile ========
      int soff[MAXI];
#pragma unroll
      for (int i = 0; i < MAXI; ++i) {
        const int u = lane + (i << 6);
        if (u < cnt4) {
          const int r = u / row4;
          const int c = u - r * row4;
          soff[i] = r * W + x_lo4 + (c << 2);
        } else soff[i] = -1;
      }
      for (int cc = 0; cc < 16; ++cc) {
        const float* plane = plane0 + (size_t)cc * planeHW;
        asm volatile("s_waitcnt lgkmcnt(0)" ::: "memory");
#pragma unroll
        for (int i = 0; i < MAXI; ++i)
          if (soff[i] >= 0) dma16(plane + soff[i], myt + (i << 8));
        asm volatile("s_waitcnt vmcnt(0)" ::: "memory");
        COMPUTE_STORE(myt, cc)
      }
    }
  } else {
    // ======== level-3 path (W=38): width-4 DMA, region provably <=340 floats → pipelined ========
    int cntS = regH * regW4;
    if (cntS > (MAXK3 << 6)) cntS = MAXK3 << 6;   // safety (analysis: <=340)
    // per-lane staging offsets, channel-invariant; -1 marks masked lanes (junk cols / tail).
    // each k-iteration always has >=1 active lane (regW4 % 4 == 0, junk cols <= 3),
    // so issued-DMA count per channel == K3 exactly.
    int soff3[MAXK3];
#pragma unroll
    for (int k = 0; k < MAXK3; ++k) {
      const int u = (k << 6) + lane;
      if (u < cntS) {
        const int r   = u / regW4;
        const int c   = u - r * regW4;
        const int col = x_lo4 + c;
        soff3[k] = (col <= Wm1) ? (r * W + col) : -1;
      } else soff3[k] = -1;
    }
    const int K3 = (cntS + 63) >> 6;   // <= 6

    // prologue: channel 0 → buffer 0
#pragma unroll
    for (int k = 0; k < MAXK3; ++k)
      if (soff3[k] >= 0) dma4(plane0 + soff3[k], myt + (k << 6));

    for (int cc = 0; cc < 16; ++cc) {
      asm volatile("s_waitcnt lgkmcnt(0)" ::: "memory");
      if (cc < 15) {
        const float* planeN = plane0 + (size_t)(cc + 1) * planeHW;
        float* bufN = myt + ((cc & 1) ? 0 : HALF_F);
#pragma unroll
        for (int k = 0; k < MAXK3; ++k)
          if (soff3[k] >= 0) dma4(planeN + soff3[k], bufN + (k << 6));
        wait_vmcnt(K3);
      } else {
        asm volatile("s_waitcnt vmcnt(0)" ::: "memory");
      }
      const float* bufC = myt + ((cc & 1) ? HALF_F : 0);
      COMPUTE_STORE(bufC, cc)
    }
  }
}

extern "C" void kernel_launch(void* const* d_in, const int* in_sizes, int n_in,
                              void* d_out, int out_size, void* d_ws, size_t ws_size,
                              hipStream_t stream) {
  const float* f0    = (const float*)d_in[0];
  const float* f1    = (const float*)d_in[1];
  const float* f2    = (const float*)d_in[2];
  const float* f3    = (const float*)d_in[3];
  const float* boxes = (const float*)d_in[4];
  const int*   bidx  = (const int*)d_in[5];
  const int N = in_sizes[5];                 // 1024 boxes
  dim3 grid(8, N);                           // 8 groups x (2 waves x 16 ch) = 256 channels
  pooler_kernel<<<grid, 128, 0, stream>>>(f0, f1, f2, f3, boxes, bidx,
                                          (float*)d_out, N);
}

// Round 2
// 279.011 us; speedup vs baseline: 1.0215x; 1.0215x over previous
//
#include <hip/hip_runtime.h>
#include <math.h>

#define TILE_F 1792    // floats per wave tile; worst-case region ~1770 (level-2... actually level-0, 125x6 ROI)
#define B448   448     // 4-deep pipeline buffer (cnt4 <= 112 float4)
#define B896   896     // 2-deep pipeline buffer (cnt4 <= 224 float4)
#define NCH    8       // channels per wave (grid.x = 16 groups of 16ch, 2 waves x 8)
#define MAXI   7       // serial-path float4 staging iterations: ceil((TILE_F/4)/64)
#define MAXIP  4       // 2-deep path float4 staging iterations: ceil((B896/4)/64)
#define MAXI4  2       // 4-deep path float4 staging iterations: ceil(112/64)
#define MAXK3  6       // level-3 path word staging iterations: region <= 340 floats <= 384

typedef __attribute__((address_space(3))) void lds_void;
typedef const __attribute__((address_space(1))) void g_void;

__device__ __forceinline__ void dma16(const float* g, float* l) {
  __builtin_amdgcn_global_load_lds((g_void*)g, (lds_void*)l, 16, 0, 0);
}
__device__ __forceinline__ void dma4(const float* g, float* l) {
  __builtin_amdgcn_global_load_lds((g_void*)g, (lds_void*)l, 4, 0, 0);
}
// Counted vmcnt wait: wave-uniform k; waiting for <=k outstanding with in-order retire
// guarantees all loads older than the newest k have completed.
__device__ __forceinline__ void wait_vmcnt(int k) {
  switch (k) {
    case 0:  asm volatile("s_waitcnt vmcnt(0)"  ::: "memory"); break;
    case 1:  asm volatile("s_waitcnt vmcnt(1)"  ::: "memory"); break;
    case 2:  asm volatile("s_waitcnt vmcnt(2)"  ::: "memory"); break;
    case 3:  asm volatile("s_waitcnt vmcnt(3)"  ::: "memory"); break;
    case 4:  asm volatile("s_waitcnt vmcnt(4)"  ::: "memory"); break;
    case 5:  asm volatile("s_waitcnt vmcnt(5)"  ::: "memory"); break;
    case 6:  asm volatile("s_waitcnt vmcnt(6)"  ::: "memory"); break;
    case 7:  asm volatile("s_waitcnt vmcnt(7)"  ::: "memory"); break;
    case 8:  asm volatile("s_waitcnt vmcnt(8)"  ::: "memory"); break;
    case 9:  asm volatile("s_waitcnt vmcnt(9)"  ::: "memory"); break;
    case 10: asm volatile("s_waitcnt vmcnt(10)" ::: "memory"); break;
    case 11: asm volatile("s_waitcnt vmcnt(11)" ::: "memory"); break;
    case 12: asm volatile("s_waitcnt vmcnt(12)" ::: "memory"); break;
    case 13: asm volatile("s_waitcnt vmcnt(13)" ::: "memory"); break;
    case 14: asm volatile("s_waitcnt vmcnt(14)" ::: "memory"); break;
    case 15: asm volatile("s_waitcnt vmcnt(15)" ::: "memory"); break;
    case 16: asm volatile("s_waitcnt vmcnt(16)" ::: "memory"); break;
    case 17: asm volatile("s_waitcnt vmcnt(17)" ::: "memory"); break;
    default: asm volatile("s_waitcnt vmcnt(18)" ::: "memory"); break;
  }
}

// 49-lane bilinear 2x2x(2x2) gather + average + store; arrays are unroll-indexed (registers).
#define COMPUTE_STORE(TP, CC)                                                  \
  if (lane < 49) {                                                             \
    float acc = 0.0f;                                                          \
    _Pragma("unroll")                                                          \
    for (int sy = 0; sy < 2; ++sy) {                                           \
      _Pragma("unroll")                                                        \
      for (int sx = 0; sx < 2; ++sx) {                                         \
        const float w00 = (TP)[rT[sy] + Cc0[sx]];                              \
        const float w01 = (TP)[rT[sy] + Cc1[sx]];                              \
        const float w10 = (TP)[rB[sy] + Cc0[sx]];                              \
        const float w11 = (TP)[rB[sy] + Cc1[sx]];                              \
        const float bil = HY[sy] * (HX[sx] * w00 + LX[sx] * w01)               \
                        + LY[sy] * (HX[sx] * w10 + LX[sx] * w11);              \
        acc += (VY[sy] * VX[sx]) * bil;                                        \
      }                                                                        \
    }                                                                          \
    outp[(CC) * 49] = acc * 0.25f;                                             \
  }

__global__ __launch_bounds__(128) void pooler_kernel(
    const float* __restrict__ f0, const float* __restrict__ f1,
    const float* __restrict__ f2, const float* __restrict__ f3,
    const float* __restrict__ boxes, const int* __restrict__ bidx,
    float* __restrict__ out, int N)
{
  __shared__ __align__(16) float tile[2][TILE_F];  // one tile per wave
  const int tid  = threadIdx.x;
  const int wave = tid >> 6, lane = tid & 63;
  const int n    = blockIdx.y;
  if (n >= N) return;

  // ---- per-box meta (wave-uniform, recomputed by every lane) ----
  const float bx1 = boxes[4*n+0], by1 = boxes[4*n+1];
  const float bx2 = boxes[4*n+2], by2 = boxes[4*n+3];
  const float area = (bx2 - bx1 + 1.0f) * (by2 - by1 + 1.0f);
  const float s    = sqrtf(area);
  int lvl = (int)floorf(4.0f + log2f(s / 224.0f + 1e-6f));
  lvl = lvl < 2 ? 2 : (lvl > 5 ? 5 : lvl);
  const int li = lvl - 2;

  int H, W; const float* feat; float scale;
  switch (li) {
    case 0:  feat = f0; H = 200; W = 304; scale = 0.25f;    break;
    case 1:  feat = f1; H = 100; W = 152; scale = 0.125f;   break;
    case 2:  feat = f2; H = 50;  W = 76;  scale = 0.0625f;  break;
    default: feat = f3; H = 25;  W = 38;  scale = 0.03125f; break;
  }
  const int b = bidx[n];
  const float x1s = bx1 * scale, y1s = by1 * scale;
  const float roiw = fmaxf(bx2 * scale - x1s, 1.0f);
  const float roih = fmaxf(by2 * scale - y1s, 1.0f);
  const float binw = roiw / 7.0f, binh = roih / 7.0f;
  const float Hm1f = (float)(H - 1), Wm1f = (float)(W - 1);
  const int   Hm1  = H - 1,          Wm1  = W - 1;

  // ---- staged region bounds (samples are monotone: first g=0.25, last g=6.75) ----
  const float yA = fminf(fmaxf(y1s + binh * 0.25f, 0.0f), Hm1f);
  const float yB = fminf(fmaxf(y1s + binh * 6.75f, 0.0f), Hm1f);
  const float xA = fminf(fmaxf(x1s + binw * 0.25f, 0.0f), Wm1f);
  const float xB = fminf(fmaxf(x1s + binw * 6.75f, 0.0f), Wm1f);
  const int y_lo  = (int)yA;
  const int y_hi  = min((int)yB + 1, Hm1);
  const int regH  = y_hi - y_lo + 1;
  const int x_lo4 = ((int)xA) & ~3;            // float4-aligned region start
  const int x_hi  = min((int)xB + 1, Wm1);
  const int row4  = ((x_hi - x_lo4 + 4) >> 2); // float4 units per row (>=1)
  const int regW4 = row4 << 2;                 // LDS row stride in floats

  // ---- per-lane bin parameters (channel-invariant; lanes 49..63 compute junk) ----
  const int bin = (lane < 49) ? lane : 0;
  const int ph = bin / 7, pw = bin - (bin / 7) * 7;
  int   rT[2], rB[2], Cc0[2], Cc1[2];
  float HY[2], LY[2], VY[2], HX[2], LX[2], VX[2];
#pragma unroll
  for (int t = 0; t < 2; ++t) {
    {   // y sample index i = 2*ph + t  →  g = ph + 0.25 + 0.5*t
      const float g  = (float)ph + 0.25f + 0.5f * (float)t;
      const float Yf = y1s + binh * g;
      VY[t] = (Yf >= -1.0f && Yf <= (float)H) ? 1.0f : 0.0f;
      const float y = fminf(fmaxf(Yf, 0.0f), Hm1f);
      const int  y0 = (int)y;
      LY[t] = y - (float)y0;  HY[t] = 1.0f - LY[t];
      rT[t] = (y0 - y_lo) * regW4;
      rB[t] = (min(y0 + 1, Hm1) - y_lo) * regW4;
    }
    {   // x sample index j = 2*pw + t
      const float g  = (float)pw + 0.25f + 0.5f * (float)t;
      const float Xf = x1s + binw * g;
      VX[t] = (Xf >= -1.0f && Xf <= (float)W) ? 1.0f : 0.0f;
      const float x = fminf(fmaxf(Xf, 0.0f), Wm1f);
      const int  x0 = (int)x;
      LX[t] = x - (float)x0;  HX[t] = 1.0f - LX[t];
      Cc0[t] = x0 - x_lo4;
      Cc1[t] = min(x0 + 1, Wm1) - x_lo4;
    }
  }

  // ---- pointers ----
  const size_t planeHW = (size_t)H * W;
  const int    cbase   = (blockIdx.x << 4) + (wave << 3);   // 8 channels per wave
  const float* plane0  = feat + ((size_t)(b * 256 + cbase)) * planeHW
                              + (size_t)y_lo * W;
  float*       outp    = out + ((size_t)n * 256 + cbase) * 49 + lane;
  float*       myt     = tile[wave];

  if (li != 3) {
    int cnt4 = regH * row4;
    if (cnt4 > TILE_F / 4) cnt4 = TILE_F / 4;   // safety (analysis: <=~443)

    if (cnt4 <= B448 / 4) {
      // ======== 4-deep pipelined path: 4 x 448-float buffers, K<=2 DMAs/channel ========
      int soff[MAXI4];
#pragma unroll
      for (int i = 0; i < MAXI4; ++i) {
        const int u = lane + (i << 6);
        if (u < cnt4) {
          const int r = u / row4;
          const int c = u - r * row4;
          soff[i] = r * W + x_lo4 + (c << 2);
        } else soff[i] = -1;
      }
      const int K = (cnt4 + 63) >> 6;   // 1..2

      // prologue: channels 0..2 → buffers 0..2
#pragma unroll
      for (int p = 0; p < 3; ++p) {
        const float* pl = plane0 + (size_t)p * planeHW;
        float* bf = myt + p * B448;
#pragma unroll
        for (int i = 0; i < MAXI4; ++i)
          if (soff[i] >= 0) dma16(pl + soff[i], bf + (i << 8));
      }

      for (int cc = 0; cc < NCH; ++cc) {
        // buffer (cc+3)&3 == (cc-1)&3 was read by compute(cc-1): drain LDS reads first
        asm volatile("s_waitcnt lgkmcnt(0)" ::: "memory");
        if (cc + 3 < NCH) {
          const float* pl = plane0 + (size_t)(cc + 3) * planeHW;
          float* bf = myt + ((cc + 3) & 3) * B448;
#pragma unroll
          for (int i = 0; i < MAXI4; ++i)
            if (soff[i] >= 0) dma16(pl + soff[i], bf + (i << 8));
        }
        const int rem = NCH - 1 - cc;            // channels still in flight after cc
        wait_vmcnt(K * (rem > 3 ? 3 : rem));     // leaves only newer channels outstanding
        const float* bufC = myt + (cc & 3) * B448;
        COMPUTE_STORE(bufC, cc)
      }
    } else if (cnt4 <= B896 / 4) {
      // ======== 2-deep pipelined path: 2 x 896-float buffers, K<=4 DMAs/channel ========
      int soff[MAXIP];
#pragma unroll
      for (int i = 0; i < MAXIP; ++i) {
        const int u = lane + (i << 6);
        if (u < cnt4) {
          const int r = u / row4;
          const int c = u - r * row4;
          soff[i] = r * W + x_lo4 + (c << 2);
        } else soff[i] = -1;
      }
      const int K = (cnt4 + 63) >> 6;   // 1..4

      // prologue: channel 0 → buffer 0
#pragma unroll
      for (int i = 0; i < MAXIP; ++i)
        if (soff[i] >= 0) dma16(plane0 + soff[i], myt + (i << 8));

      for (int cc = 0; cc < NCH; ++cc) {
        asm volatile("s_waitcnt lgkmcnt(0)" ::: "memory");
        if (cc + 1 < NCH) {
          const float* pl = plane0 + (size_t)(cc + 1) * planeHW;
          float* bf = myt + ((cc + 1) & 1) * B896;
#pragma unroll
          for (int i = 0; i < MAXIP; ++i)
            if (soff[i] >= 0) dma16(pl + soff[i], bf + (i << 8));
          wait_vmcnt(K);
        } else {
          asm volatile("s_waitcnt vmcnt(0)" ::: "memory");
        }
        const float* bufC = myt + (cc & 1) * B896;
        COMPUTE_STORE(bufC, cc)
      }
    } else {
      // ======== serial fallback (rare large level-0 boxes): full 1792-float tile ========
      int soff[MAXI];
#pragma unroll
      for (int i = 0; i < MAXI; ++i) {
        const int u = lane + (i << 6);
        if (u < cnt4) {
          const int r = u / row4;
          const int c = u - r * row4;
          soff[i] = r * W + x_lo4 + (c << 2);
        } else soff[i] = -1;
      }
      for (int cc = 0; cc < NCH; ++cc) {
        const float* plane = plane0 + (size_t)cc * planeHW;
        asm volatile("s_waitcnt lgkmcnt(0)" ::: "memory");
#pragma unroll
        for (int i = 0; i < MAXI; ++i)
          if (soff[i] >= 0) dma16(plane + soff[i], myt + (i << 8));
        asm volatile("s_waitcnt vmcnt(0)" ::: "memory");
        COMPUTE_STORE(myt, cc)
      }
    }
  } else {
    // ======== level-3 path (W=38): width-4 DMA, region provably <=340 floats → 4-deep ========
    int cntS = regH * regW4;
    if (cntS > (MAXK3 << 6)) cntS = MAXK3 << 6;   // safety (analysis: <=340 <= 384 <= B448)
    // per-lane staging offsets, channel-invariant; -1 marks masked lanes (junk cols / tail).
    // each k-iteration below cntS has >=1 active lane (junk cols <= 3, regW4 >= 4),
    // so issued-DMA count per channel == K3 exactly.
    int soff3[MAXK3];
#pragma unroll
    for (int k = 0; k < MAXK3; ++k) {
      const int u = (k << 6) + lane;
      if (u < cntS) {
        const int r   = u / regW4;
        const int c   = u - r * regW4;
        const int col = x_lo4 + c;
        soff3[k] = (col <= Wm1) ? (r * W + col) : -1;
      } else soff3[k] = -1;
    }
    const int K3 = (cntS + 63) >> 6;   // 1..6

    // prologue: channels 0..2 → buffers 0..2
#pragma unroll
    for (int p = 0; p < 3; ++p) {
      const float* pl = plane0 + (size_t)p * planeHW;
      float* bf = myt + p * B448;
#pragma unroll
      for (int k = 0; k < MAXK3; ++k)
        if (soff3[k] >= 0) dma4(pl + soff3[k], bf + (k << 6));
    }

    for (int cc = 0; cc < NCH; ++cc) {
      asm volatile("s_waitcnt lgkmcnt(0)" ::: "memory");
      if (cc + 3 < NCH) {
        const float* pl = plane0 + (size_t)(cc + 3) * planeHW;
        float* bf = myt + ((cc + 3) & 3) * B448;
#pragma unroll
        for (int k = 0; k < MAXK3; ++k)
          if (soff3[k] >= 0) dma4(pl + soff3[k], bf + (k << 6));
      }
      const int rem = NCH - 1 - cc;
      wait_vmcnt(K3 * (rem > 3 ? 3 : rem));
      const float* bufC = myt + (cc & 3) * B448;
      COMPUTE_STORE(bufC, cc)
    }
  }
}

extern "C" void kernel_launch(void* const* d_in, const int* in_sizes, int n_in,
                              void* d_out, int out_size, void* d_ws, size_t ws_size,
                              hipStream_t stream) {
  const float* f0    = (const float*)d_in[0];
  const float* f1    = (const float*)d_in[1];
  const float* f2    = (const float*)d_in[2];
  const float* f3    = (const float*)d_in[3];
  const float* boxes = (const float*)d_in[4];
  const int*   bidx  = (const int*)d_in[5];
  const int N = in_sizes[5];                 // 1024 boxes
  dim3 grid(16, N);                          // 16 groups x (2 waves x 8 ch) = 256 channels
  pooler_kernel<<<grid, 128, 0, stream>>>(f0, f1, f2, f3, boxes, bidx,
                                          (float*)d_out, N);
}